// Round 1
// baseline (26.380 us; speedup 1.0000x reference)
//
#include <hip/hip_runtime.h>

#define LPTS  2048   // points per row
#define NSEG  2047   // increments per row
#define TPB   256
#define STEPS 8      // segments per thread (256*8 = 2048 >= 2047)
#define NBATCH 2048

// a := a (tensor-)⊗ sig(segment with increment v)   [depth-3 truncated]
__device__ __forceinline__ void chen_step(float a[14], float vx, float vy) {
    const float a1x = a[0], a1y = a[1];
    const float a2xx = a[2], a2xy = a[3], a2yx = a[4], a2yy = a[5];
    // g2_{jk} = 0.5 v_j v_k ; g3_{ijk} = v_i v_j v_k / 6
    const float qxx = 0.5f * vx * vx;
    const float qxy = 0.5f * vx * vy;
    const float qyy = 0.5f * vy * vy;
    // a1_i*g2_{jk} + g3_{ijk} = q_{jk} * (a1_i + v_i/3)
    const float wx = fmaf(vx, (1.0f / 3.0f), a1x);
    const float wy = fmaf(vy, (1.0f / 3.0f), a1y);
    // a3_{ijk} += a2_{ij} v_k + w_i q_{jk}
    a[6]  += a2xx * vx + wx * qxx;   // xxx
    a[7]  += a2xx * vy + wx * qxy;   // xxy
    a[8]  += a2xy * vx + wx * qxy;   // xyx (q_yx == q_xy)
    a[9]  += a2xy * vy + wx * qyy;   // xyy
    a[10] += a2yx * vx + wy * qxx;   // yxx
    a[11] += a2yx * vy + wy * qxy;   // yxy
    a[12] += a2yy * vx + wy * qxy;   // yyx
    a[13] += a2yy * vy + wy * qyy;   // yyy
    // a2_{ij} += (a1_i + 0.5 v_i) v_j
    const float ux = fmaf(vx, 0.5f, a1x);
    const float uy = fmaf(vy, 0.5f, a1y);
    a[2] = fmaf(ux, vx, a[2]);
    a[3] = fmaf(ux, vy, a[3]);
    a[4] = fmaf(uy, vx, a[4]);
    a[5] = fmaf(uy, vy, a[5]);
    // a1 += v
    a[0] = a1x + vx;
    a[1] = a1y + vy;
}

// b := a ⊗ b  (a is the left/earlier signature). Chen's identity, depth 3.
__device__ __forceinline__ void chen_combine(const float a[14], float b[14]) {
    float c[14];
    c[0] = a[0] + b[0];
    c[1] = a[1] + b[1];
    // c2_{ij} = a2_{ij} + a1_i b1_j + b2_{ij}
    c[2] = a[2] + a[0] * b[0] + b[2];
    c[3] = a[3] + a[0] * b[1] + b[3];
    c[4] = a[4] + a[1] * b[0] + b[4];
    c[5] = a[5] + a[1] * b[1] + b[5];
    // c3_{ijk} = a3_{ijk} + a2_{ij} b1_k + a1_i b2_{jk} + b3_{ijk}
    c[6]  = a[6]  + a[2] * b[0] + a[0] * b[2] + b[6];
    c[7]  = a[7]  + a[2] * b[1] + a[0] * b[3] + b[7];
    c[8]  = a[8]  + a[3] * b[0] + a[0] * b[4] + b[8];
    c[9]  = a[9]  + a[3] * b[1] + a[0] * b[5] + b[9];
    c[10] = a[10] + a[4] * b[0] + a[1] * b[2] + b[10];
    c[11] = a[11] + a[4] * b[1] + a[1] * b[3] + b[11];
    c[12] = a[12] + a[5] * b[0] + a[1] * b[4] + b[12];
    c[13] = a[13] + a[5] * b[1] + a[1] * b[5] + b[13];
#pragma unroll
    for (int i = 0; i < 14; ++i) b[i] = c[i];
}

// pointwise MLP 1 -> 8 -> 2 (ReLU between): p = w2 @ relu(w1*x + b1) + b2
__device__ __forceinline__ void augment(float x,
                                        const float W1[8], const float B1[8],
                                        const float W2x[8], const float W2y[8],
                                        float B2x, float B2y,
                                        float& px, float& py) {
    float ox = B2x, oy = B2y;
#pragma unroll
    for (int c = 0; c < 8; ++c) {
        float h = fmaxf(fmaf(W1[c], x, B1[c]), 0.0f);
        ox = fmaf(W2x[c], h, ox);
        oy = fmaf(W2y[c], h, oy);
    }
    px = ox;
    py = oy;
}

__global__ __launch_bounds__(TPB) void sig_scan_kernel(
    const float* __restrict__ x, const float* __restrict__ w1,
    const float* __restrict__ b1, const float* __restrict__ w2,
    const float* __restrict__ b2, const float* __restrict__ wout,
    float* __restrict__ out) {
    __shared__ float xs[LPTS];        // x row stage, later reused as output stage
    __shared__ float sc[TPB][15];     // scan buffer, stride 15 -> conflict-free

    const int t = threadIdx.x;
    const int brow = blockIdx.x;
    const float* __restrict__ xrow = x + (size_t)brow * LPTS;

    // coalesced row load: 2048 floats = 256 threads x 2 float4
    {
        const float4* xr4 = reinterpret_cast<const float4*>(xrow);
        float4* xs4 = reinterpret_cast<float4*>(xs);
        xs4[t] = xr4[t];
        xs4[t + TPB] = xr4[t + TPB];
    }

    // uniform weights (uniform addresses -> scalar loads/SGPRs)
    float W1[8], B1[8], W2x[8], W2y[8];
#pragma unroll
    for (int c = 0; c < 8; ++c) {
        W1[c] = w1[c];
        B1[c] = b1[c];
        W2x[c] = w2[c];
        W2y[c] = w2[8 + c];
    }
    const float B2x = b2[0], B2y = b2[1];
    float WO[14];
#pragma unroll
    for (int i = 0; i < 14; ++i) WO[i] = wout[i];

    __syncthreads();

    // ---- phase 1: local chunk signature (8 increments/thread) ----
    const int n0 = t * STEPS;
    float vx[STEPS], vy[STEPS];
    float s[14];
#pragma unroll
    for (int i = 0; i < 14; ++i) s[i] = 0.0f;

    float ppx, ppy;
    augment(xs[n0], W1, B1, W2x, W2y, B2x, B2y, ppx, ppy);
#pragma unroll
    for (int k = 0; k < STEPS; ++k) {
        int pidx = n0 + k + 1;
        pidx = pidx > (LPTS - 1) ? (LPTS - 1) : pidx;  // clamp => v=0 for padded step
        float px, py;
        augment(xs[pidx], W1, B1, W2x, W2y, B2x, B2y, px, py);
        vx[k] = px - ppx;
        vy[k] = py - ppy;
        ppx = px;
        ppy = py;
        chen_step(s, vx[k], vy[k]);
    }

    // ---- phase 2: workgroup inclusive scan (Hillis-Steele, Chen combine) ----
#pragma unroll
    for (int i = 0; i < 14; ++i) sc[t][i] = s[i];
    __syncthreads();
    for (int off = 1; off < TPB; off <<= 1) {
        float p[14];
        const bool has = (t >= off);
        if (has) {
#pragma unroll
            for (int i = 0; i < 14; ++i) p[i] = sc[t - off][i];
        }
        __syncthreads();
        if (has) {
            chen_combine(p, s);  // s = p ⊗ s  (earlier chunk on the left)
#pragma unroll
            for (int i = 0; i < 14; ++i) sc[t][i] = s[i];
        }
        __syncthreads();
    }

    // exclusive carry for this thread = inclusive scan of thread t-1
    float a[14];
    if (t == 0) {
#pragma unroll
        for (int i = 0; i < 14; ++i) a[i] = 0.0f;
    } else {
#pragma unroll
        for (int i = 0; i < 14; ++i) a[i] = sc[t - 1][i];
    }

    // ---- phase 3: replay with carry, project, stage outputs ----
    float* outbuf = xs;  // x row no longer needed
#pragma unroll
    for (int k = 0; k < STEPS; ++k) {
        chen_step(a, vx[k], vy[k]);
        float o = WO[0] * a[0];
#pragma unroll
        for (int i = 1; i < 14; ++i) o = fmaf(WO[i], a[i], o);
        const int n = n0 + k;
        if (n < NSEG) outbuf[n] = o;
    }
    __syncthreads();

    // coalesced store of the output row
    float* __restrict__ orow = out + (size_t)brow * NSEG;
    for (int i = t; i < NSEG; i += TPB) orow[i] = outbuf[i];
}

extern "C" void kernel_launch(void* const* d_in, const int* in_sizes, int n_in,
                              void* d_out, int out_size, void* d_ws, size_t ws_size,
                              hipStream_t stream) {
    const float* x  = (const float*)d_in[0];
    const float* w1 = (const float*)d_in[1];
    const float* b1 = (const float*)d_in[2];
    const float* w2 = (const float*)d_in[3];
    const float* b2 = (const float*)d_in[4];
    const float* wo = (const float*)d_in[5];
    float* out = (float*)d_out;
    sig_scan_kernel<<<NBATCH, TPB, 0, stream>>>(x, w1, b1, w2, b2, wo, out);
}

// Round 2
// 25.322 us; speedup vs baseline: 1.0418x; 1.0418x over previous
//
#include <hip/hip_runtime.h>

#define LPTS  2048   // points per row
#define NSEG  2047   // increments per row
#define TPB   256
#define STEPS 8      // segments per thread (256*8 = 2048 >= 2047)
#define NBATCH 2048
#define NWAVE (TPB / 64)

// a := a ⊗ sig(segment with increment v)   [depth-3 truncated tensor algebra]
__device__ __forceinline__ void chen_step(float a[14], float vx, float vy) {
    const float a1x = a[0], a1y = a[1];
    const float a2xx = a[2], a2xy = a[3], a2yx = a[4], a2yy = a[5];
    const float qxx = 0.5f * vx * vx;
    const float qxy = 0.5f * vx * vy;
    const float qyy = 0.5f * vy * vy;
    // a1_i*g2_{jk} + g3_{ijk} = q_{jk} * (a1_i + v_i/3)
    const float wx = fmaf(vx, (1.0f / 3.0f), a1x);
    const float wy = fmaf(vy, (1.0f / 3.0f), a1y);
    a[6]  += a2xx * vx + wx * qxx;
    a[7]  += a2xx * vy + wx * qxy;
    a[8]  += a2xy * vx + wx * qxy;
    a[9]  += a2xy * vy + wx * qyy;
    a[10] += a2yx * vx + wy * qxx;
    a[11] += a2yx * vy + wy * qxy;
    a[12] += a2yy * vx + wy * qxy;
    a[13] += a2yy * vy + wy * qyy;
    const float ux = fmaf(vx, 0.5f, a1x);
    const float uy = fmaf(vy, 0.5f, a1y);
    a[2] = fmaf(ux, vx, a[2]);
    a[3] = fmaf(ux, vy, a[3]);
    a[4] = fmaf(uy, vx, a[4]);
    a[5] = fmaf(uy, vy, a[5]);
    a[0] = a1x + vx;
    a[1] = a1y + vy;
}

// b := a ⊗ b  (a earlier, b later). Chen's identity, depth 3.
__device__ __forceinline__ void chen_combine(const float a[14], float b[14]) {
    float c[14];
    c[0] = a[0] + b[0];
    c[1] = a[1] + b[1];
    c[2] = a[2] + a[0] * b[0] + b[2];
    c[3] = a[3] + a[0] * b[1] + b[3];
    c[4] = a[4] + a[1] * b[0] + b[4];
    c[5] = a[5] + a[1] * b[1] + b[5];
    c[6]  = a[6]  + a[2] * b[0] + a[0] * b[2] + b[6];
    c[7]  = a[7]  + a[2] * b[1] + a[0] * b[3] + b[7];
    c[8]  = a[8]  + a[3] * b[0] + a[0] * b[4] + b[8];
    c[9]  = a[9]  + a[3] * b[1] + a[0] * b[5] + b[9];
    c[10] = a[10] + a[4] * b[0] + a[1] * b[2] + b[10];
    c[11] = a[11] + a[4] * b[1] + a[1] * b[3] + b[11];
    c[12] = a[12] + a[5] * b[0] + a[1] * b[4] + b[12];
    c[13] = a[13] + a[5] * b[1] + a[1] * b[5] + b[13];
#pragma unroll
    for (int i = 0; i < 14; ++i) b[i] = c[i];
}

// pointwise MLP 1 -> 8 -> 2 (ReLU between)
__device__ __forceinline__ void augment(float x,
                                        const float W1[8], const float B1[8],
                                        const float W2x[8], const float W2y[8],
                                        float B2x, float B2y,
                                        float& px, float& py) {
    float ox = B2x, oy = B2y;
#pragma unroll
    for (int c = 0; c < 8; ++c) {
        float h = fmaxf(fmaf(W1[c], x, B1[c]), 0.0f);
        ox = fmaf(W2x[c], h, ox);
        oy = fmaf(W2y[c], h, oy);
    }
    px = ox;
    py = oy;
}

__global__ __launch_bounds__(TPB) void sig_scan_kernel(
    const float* __restrict__ x, const float* __restrict__ w1,
    const float* __restrict__ b1, const float* __restrict__ w2,
    const float* __restrict__ b2, const float* __restrict__ wout,
    float* __restrict__ out) {
    __shared__ float wsum[NWAVE][15];  // per-wave chunk totals (pad 15)

    const int t = threadIdx.x;
    const int lane = t & 63;
    const int wv = t >> 6;
    const int brow = blockIdx.x;
    const float* __restrict__ xrow = x + (size_t)brow * LPTS;

    // ---- direct global load of this thread's 9 points (contiguous per wave) ----
    const int n0 = t * STEPS;
    const float4 xa = *reinterpret_cast<const float4*>(xrow + n0);
    const float4 xb = *reinterpret_cast<const float4*>(xrow + n0 + 4);
    const int i8 = (n0 + 8 > LPTS - 1) ? (LPTS - 1) : (n0 + 8);
    const float x8 = xrow[i8];
    float xv[9] = {xa.x, xa.y, xa.z, xa.w, xb.x, xb.y, xb.z, xb.w, x8};

    // uniform weights (uniform addresses -> scalar loads)
    float W1[8], B1[8], W2x[8], W2y[8];
#pragma unroll
    for (int c = 0; c < 8; ++c) {
        W1[c] = w1[c];
        B1[c] = b1[c];
        W2x[c] = w2[c];
        W2y[c] = w2[8 + c];
    }
    const float B2x = b2[0], B2y = b2[1];
    float WO[14];
#pragma unroll
    for (int i = 0; i < 14; ++i) WO[i] = wout[i];

    // ---- phase 1: augment points, increments, local chunk signature ----
    float vx[STEPS], vy[STEPS];
    float s[14];
#pragma unroll
    for (int i = 0; i < 14; ++i) s[i] = 0.0f;

    float ppx, ppy;
    augment(xv[0], W1, B1, W2x, W2y, B2x, B2y, ppx, ppy);
#pragma unroll
    for (int k = 0; k < STEPS; ++k) {
        float px, py;
        augment(xv[k + 1], W1, B1, W2x, W2y, B2x, B2y, px, py);
        vx[k] = px - ppx;
        vy[k] = py - ppy;
        ppx = px;
        ppy = py;
        chen_step(s, vx[k], vy[k]);
    }
    // (t==255,k==7 has xv[8]==xv[7+1] clamped -> v==0 -> identity segment)

    // ---- phase 2a: wave64 inclusive shuffle scan (no barriers) ----
#pragma unroll
    for (int off = 1; off < 64; off <<= 1) {
        float p[14];
#pragma unroll
        for (int i = 0; i < 14; ++i) p[i] = __shfl_up(s[i], (unsigned)off);
        if (lane >= off) chen_combine(p, s);
    }

    // ---- phase 2b: cross-wave combine (one barrier) ----
    if (lane == 63) {
#pragma unroll
        for (int i = 0; i < 14; ++i) wsum[wv][i] = s[i];
    }
    __syncthreads();

    // per-lane exclusive prefix within wave
    float a[14];
    {
        float e[14];
#pragma unroll
        for (int i = 0; i < 14; ++i) e[i] = __shfl_up(s[i], 1u);
#pragma unroll
        for (int i = 0; i < 14; ++i) a[i] = (lane == 0) ? 0.0f : e[i];
    }
    // prepend earlier waves' totals in order: a = T0 ⊗ ... ⊗ T_{wv-1} ⊗ a
    for (int w = wv - 1; w >= 0; --w) {
        float tw[14];
#pragma unroll
        for (int i = 0; i < 14; ++i) tw[i] = wsum[w][i];  // broadcast read
        chen_combine(tw, a);
    }

    // ---- phase 3: replay with carry, project, direct store ----
    float og[STEPS];
#pragma unroll
    for (int k = 0; k < STEPS; ++k) {
        chen_step(a, vx[k], vy[k]);
        float o = WO[0] * a[0];
#pragma unroll
        for (int i = 1; i < 14; ++i) o = fmaf(WO[i], a[i], o);
        og[k] = o;
    }

    float* __restrict__ orow = out + (size_t)brow * NSEG;
#pragma unroll
    for (int k = 0; k < STEPS; ++k) {
        const int n = n0 + k;
        if (n < NSEG) orow[n] = og[k];
    }
}

extern "C" void kernel_launch(void* const* d_in, const int* in_sizes, int n_in,
                              void* d_out, int out_size, void* d_ws, size_t ws_size,
                              hipStream_t stream) {
    const float* x  = (const float*)d_in[0];
    const float* w1 = (const float*)d_in[1];
    const float* b1 = (const float*)d_in[2];
    const float* w2 = (const float*)d_in[3];
    const float* b2 = (const float*)d_in[4];
    const float* wo = (const float*)d_in[5];
    float* out = (float*)d_out;
    sig_scan_kernel<<<NBATCH, TPB, 0, stream>>>(x, w1, b1, w2, b2, wo, out);
}